// Round 3
// baseline (2805.056 us; speedup 1.0000x reference)
//
#include <hip/hip_runtime.h>

// Jansen-Rit neural mass model, R independent regions, Euler integration.
// One lane per region (4 wave64s). Serial 20000-step loop.
// R3: R1/R2 were bound by UNCOALESCED history stores (3x float2 at stride
// 24B/lane -> ~48 memory transactions per store instr -> ~150 cyc/step of
// TA processing; rocprof identical 1686.9us across R1/R2 despite unroll).
// Fix: stage KC=16 steps of state in LDS, then flush each step's 1536B
// block-segment as 3 coalesced 512B dwordx2 stores.

#define RLOG2E 1.44269504088896340736f
#define KC 16

__global__ __launch_bounds__(64)
void jansen_kernel(const float* __restrict__ init_state,
                   const float* __restrict__ p_dt,
                   const int*   __restrict__ p_nsteps,
                   const float* __restrict__ pA,    const float* __restrict__ pa,
                   const float* __restrict__ pB,    const float* __restrict__ pb,
                   const float* __restrict__ pc1,   const float* __restrict__ pc2,
                   const float* __restrict__ pc3,   const float* __restrict__ pc4,
                   const float* __restrict__ pvmax, const float* __restrict__ pv0,
                   const float* __restrict__ pr,    const float* __restrict__ pstd,
                   float* __restrict__ out, int R)
{
    __shared__ float lds[KC * 64 * 6];

    const int lane = threadIdx.x;
    const int blk  = blockIdx.x;
    const int reg  = blk * 64 + lane;
    const int lreg = (reg < R) ? reg : (R - 1);   // clamp: inactive lanes integrate a copy

    const float dt     = *p_dt;
    const int   nsteps = *p_nsteps;
    const float A = *pA, a = *pa, B = *pB, b = *pb;
    const float c1 = *pc1, c2 = *pc2, c3 = *pc3, c4 = *pc4;
    const float vmax = *pvmax, v0 = *pv0, rsl = *pr, std_in = *pstd;

    // sig(x) = vmax / (1 + exp(r*(v0-x))) = vmax * rcp(1 + exp2(cl2*(v0-x)))
    const float cl2 = rsl * RLOG2E;
    const float cv0 = cl2 * v0;
    const float nE  = -cl2;        // arg = fma(nE,  E-I, cv0)
    const float nM1 = -cl2 * c1;   // arg = fma(nM1, M,   cv0)
    const float nM3 = -cl2 * c3;   // arg = fma(nM3, M,   cv0)

    // Euler update folded: Xv' = kXv*Xv + kSig*rcp + kX*X (+ kIn)
    const float kMv = 1.0f - 2.0f * a * dt;
    const float kIv = 1.0f - 2.0f * b * dt;
    const float kM  = -dt * a * a;
    const float kI  = -dt * b * b;
    const float kSE  = dt * A * a * vmax;
    const float kSM1 = dt * A * a * c2 * vmax;
    const float kSM3 = dt * B * b * c4 * vmax;
    const float kIn  = dt * A * a * std_in;

    float M  = init_state[lreg * 6 + 0];
    float E  = init_state[lreg * 6 + 1];
    float I  = init_state[lreg * 6 + 2];
    float Mv = init_state[lreg * 6 + 3];
    float Ev = init_state[lreg * 6 + 4];
    float Iv = init_state[lreg * 6 + 5];

    const int R6   = R * 6;                       // floats per history row
    const int nact = min(64, R - blk * 64);       // active regions in this block
    const int S    = nact * 6;                    // valid dwords in this block's segment
    float* rowBase = out + R6 + (size_t)blk * 64 * 6;  // row 0, this block's segment

    #define STEP(u)                                                             \
    do {                                                                        \
        float eE  = __builtin_amdgcn_exp2f(fmaf(nE,  E - I, cv0));              \
        float eM1 = __builtin_amdgcn_exp2f(fmaf(nM1, M,     cv0));              \
        float eM3 = __builtin_amdgcn_exp2f(fmaf(nM3, M,     cv0));              \
        float rE  = __builtin_amdgcn_rcpf(1.0f + eE);                           \
        float rM1 = __builtin_amdgcn_rcpf(1.0f + eM1);                          \
        float rM3 = __builtin_amdgcn_rcpf(1.0f + eM3);                          \
        float nMv_ = fmaf(kMv, Mv, fmaf(kSE,  rE,  kM * M));                    \
        float nEv_ = fmaf(kMv, Ev, fmaf(kSM1, rM1, fmaf(kM, E, kIn)));          \
        float nIv_ = fmaf(kIv, Iv, fmaf(kSM3, rM3, kI * I));                    \
        float nM_  = fmaf(dt, Mv, M);                                           \
        float nE_  = fmaf(dt, Ev, E);                                           \
        float nI_  = fmaf(dt, Iv, I);                                           \
        M = nM_; E = nE_; I = nI_; Mv = nMv_; Ev = nEv_; Iv = nIv_;             \
        float* l = lds + (u) * 384 + lane * 6;                                  \
        ((float2*)l)[0] = make_float2(M, E);                                    \
        ((float2*)l)[1] = make_float2(I, Mv);                                   \
        ((float2*)l)[2] = make_float2(Ev, Iv);                                  \
    } while (0)

    const int nchunks = nsteps / KC;
    for (int c = 0; c < nchunks; ++c) {
        #pragma unroll
        for (int u = 0; u < KC; ++u) {
            STEP(u);
        }
        __syncthreads();   // single wave: compiles to waitcnt (ds writes visible)

        float* rb = rowBase + (size_t)(c * KC) * R6;
        if (S == 384) {
            // full block: unpredicated coalesced flush
            #pragma unroll
            for (int u = 0; u < KC; ++u) {
                const float* l = lds + u * 384;
                float*       g = rb + (size_t)u * R6;
                #pragma unroll
                for (int p = 0; p < 3; ++p) {
                    int d = p * 128 + 2 * lane;
                    *(float2*)(g + d) = *(const float2*)(l + d);
                }
            }
        } else {
            #pragma unroll
            for (int u = 0; u < KC; ++u) {
                const float* l = lds + u * 384;
                float*       g = rb + (size_t)u * R6;
                #pragma unroll
                for (int p = 0; p < 3; ++p) {
                    int d = p * 128 + 2 * lane;
                    if (d < S) *(float2*)(g + d) = *(const float2*)(l + d);
                }
            }
        }
        __syncthreads();
    }

    // remainder steps (nsteps % KC): direct (uncoalesced) stores, rare path
    for (int s = nchunks * KC; s < nsteps; ++s) {
        STEP(0);
        if (reg < R) {
            float* g = out + R6 + (size_t)s * R6 + (size_t)reg * 6;
            const float* l = lds + lane * 6;
            ((float2*)g)[0] = ((const float2*)l)[0];
            ((float2*)g)[1] = ((const float2*)l)[1];
            ((float2*)g)[2] = ((const float2*)l)[2];
        }
    }
    #undef STEP

    if (reg < R) {
        float* fin = out + (size_t)reg * 6;
        ((float2*)fin)[0] = make_float2(M, E);
        ((float2*)fin)[1] = make_float2(I, Mv);
        ((float2*)fin)[2] = make_float2(Ev, Iv);
    }
}

extern "C" void kernel_launch(void* const* d_in, const int* in_sizes, int n_in,
                              void* d_out, int out_size, void* d_ws, size_t ws_size,
                              hipStream_t stream)
{
    const float* init = (const float*)d_in[0];
    const float* dt   = (const float*)d_in[1];
    const int*   ns   = (const int*)d_in[2];
    const int R = in_sizes[0] / 6;  // 200

    dim3 grid((R + 63) / 64), block(64);
    jansen_kernel<<<grid, block, 0, stream>>>(
        init, dt, ns,
        (const float*)d_in[3],  (const float*)d_in[4],
        (const float*)d_in[5],  (const float*)d_in[6],
        (const float*)d_in[7],  (const float*)d_in[8],
        (const float*)d_in[9],  (const float*)d_in[10],
        (const float*)d_in[11], (const float*)d_in[12],
        (const float*)d_in[13], (const float*)d_in[14],
        (float*)d_out, R);
}

// Round 4
// 1585.675 us; speedup vs baseline: 1.7690x; 1.7690x over previous
//
#include <hip/hip_runtime.h>

// Jansen-Rit neural mass model, R independent regions, Euler integration.
// R4: producer/consumer wave split. R3 showed memory-op completion latency
// (store acks + barrier drains) serializes with compute when a single wave
// does both. Now: wave 0 = pure-compute integrator (VALU + ds_write only),
// wave 1 = flusher (LDS -> 96-reg batch -> 48 coalesced dwordx2 stores),
// double-buffered KC=16-step LDS chunks, one barrier per chunk.

#define RLOG2E 1.44269504088896340736f
#define KC 16

__global__ __launch_bounds__(128)
void jansen_kernel(const float* __restrict__ init_state,
                   const float* __restrict__ p_dt,
                   const int*   __restrict__ p_nsteps,
                   const float* __restrict__ pA,    const float* __restrict__ pa,
                   const float* __restrict__ pB,    const float* __restrict__ pb,
                   const float* __restrict__ pc1,   const float* __restrict__ pc2,
                   const float* __restrict__ pc3,   const float* __restrict__ pc4,
                   const float* __restrict__ pvmax, const float* __restrict__ pv0,
                   const float* __restrict__ pr,    const float* __restrict__ pstd,
                   float* __restrict__ out, int R)
{
    __shared__ float lds[2][KC * 384];

    const int tid  = threadIdx.x;
    const int wid  = tid >> 6;        // 0 = compute wave, 1 = flusher wave
    const int lane = tid & 63;
    const int blk  = blockIdx.x;
    const int reg  = blk * 64 + lane;
    const int lreg = (reg < R) ? reg : (R - 1);

    const float dt     = *p_dt;
    const int   nsteps = *p_nsteps;
    const float A = *pA, a = *pa, B = *pB, b = *pb;
    const float c1 = *pc1, c2 = *pc2, c3 = *pc3, c4 = *pc4;
    const float vmax = *pvmax, v0 = *pv0, rsl = *pr, std_in = *pstd;

    // sig(x) = vmax / (1 + exp(r*(v0-x))) = vmax * rcp(1 + exp2(cl2*(v0-x)))
    const float cl2 = rsl * RLOG2E;
    const float cv0 = cl2 * v0;
    const float nE  = -cl2;
    const float nM1 = -cl2 * c1;
    const float nM3 = -cl2 * c3;

    const float kMv = 1.0f - 2.0f * a * dt;
    const float kIv = 1.0f - 2.0f * b * dt;
    const float kM  = -dt * a * a;
    const float kI  = -dt * b * b;
    const float kSE  = dt * A * a * vmax;
    const float kSM1 = dt * A * a * c2 * vmax;
    const float kSM3 = dt * B * b * c4 * vmax;
    const float kIn  = dt * A * a * std_in;

    float M  = init_state[lreg * 6 + 0];
    float E  = init_state[lreg * 6 + 1];
    float I  = init_state[lreg * 6 + 2];
    float Mv = init_state[lreg * 6 + 3];
    float Ev = init_state[lreg * 6 + 4];
    float Iv = init_state[lreg * 6 + 5];

    const int R6   = R * 6;
    const int nact = min(64, R - blk * 64);
    const int S    = nact * 6;                       // valid dwords per step-row segment
    float* rowBase = out + R6 + (size_t)blk * 64 * 6;
    const int nchunks = nsteps / KC;

    #define STEP()                                                              \
    do {                                                                        \
        float eE  = __builtin_amdgcn_exp2f(fmaf(nE,  E - I, cv0));              \
        float eM1 = __builtin_amdgcn_exp2f(fmaf(nM1, M,     cv0));              \
        float eM3 = __builtin_amdgcn_exp2f(fmaf(nM3, M,     cv0));              \
        float rE  = __builtin_amdgcn_rcpf(1.0f + eE);                           \
        float rM1 = __builtin_amdgcn_rcpf(1.0f + eM1);                          \
        float rM3 = __builtin_amdgcn_rcpf(1.0f + eM3);                          \
        float nMv_ = fmaf(kMv, Mv, fmaf(kSE,  rE,  kM * M));                    \
        float nEv_ = fmaf(kMv, Ev, fmaf(kSM1, rM1, fmaf(kM, E, kIn)));          \
        float nIv_ = fmaf(kIv, Iv, fmaf(kSM3, rM3, kI * I));                    \
        float nM_  = fmaf(dt, Mv, M);                                           \
        float nE_  = fmaf(dt, Ev, E);                                           \
        float nI_  = fmaf(dt, Iv, I);                                           \
        M = nM_; E = nE_; I = nI_; Mv = nMv_; Ev = nEv_; Iv = nIv_;             \
    } while (0)

    #define FLUSH(cc)                                                           \
    do {                                                                        \
        const float* bp = lds[(cc) & 1];                                        \
        float* rb = rowBase + (size_t)((cc) * KC) * R6;                         \
        if (S == 384) {                                                         \
            float2 v[KC * 3];                                                   \
            _Pragma("unroll")                                                   \
            for (int u = 0; u < KC; ++u)                                        \
                _Pragma("unroll")                                               \
                for (int p = 0; p < 3; ++p)                                     \
                    v[u * 3 + p] = *(const float2*)(bp + u * 384 + p * 128 + 2 * lane); \
            _Pragma("unroll")                                                   \
            for (int u = 0; u < KC; ++u)                                        \
                _Pragma("unroll")                                               \
                for (int p = 0; p < 3; ++p)                                     \
                    *(float2*)(rb + (size_t)u * R6 + p * 128 + 2 * lane) = v[u * 3 + p]; \
        } else {                                                                \
            _Pragma("unroll")                                                   \
            for (int u = 0; u < KC; ++u) {                                      \
                _Pragma("unroll")                                               \
                for (int p = 0; p < 3; ++p) {                                   \
                    int d = p * 128 + 2 * lane;                                 \
                    if (d < S)                                                  \
                        *(float2*)(rb + (size_t)u * R6 + d) = *(const float2*)(bp + u * 384 + d); \
                }                                                               \
            }                                                                   \
        }                                                                       \
    } while (0)

    for (int c = 0; c < nchunks; ++c) {
        if (wid == 0) {
            float* buf = lds[c & 1];
            #pragma unroll
            for (int u = 0; u < KC; ++u) {
                STEP();
                float* l = buf + u * 384 + lane * 6;
                ((float2*)l)[0] = make_float2(M, E);
                ((float2*)l)[1] = make_float2(I, Mv);
                ((float2*)l)[2] = make_float2(Ev, Iv);
            }
        } else if (c > 0) {
            FLUSH(c - 1);
        }
        __syncthreads();
    }
    if (wid == 1 && nchunks > 0) {
        FLUSH(nchunks - 1);
    }

    // tail steps (nsteps % KC) — direct stores, compute wave only (none for 20000/16)
    for (int s = nchunks * KC; s < nsteps; ++s) {
        if (wid == 0) {
            STEP();
            if (reg < R) {
                float* g = out + R6 + (size_t)s * R6 + (size_t)reg * 6;
                ((float2*)g)[0] = make_float2(M, E);
                ((float2*)g)[1] = make_float2(I, Mv);
                ((float2*)g)[2] = make_float2(Ev, Iv);
            }
        }
    }
    #undef STEP
    #undef FLUSH

    if (wid == 0 && reg < R) {
        float* fin = out + (size_t)reg * 6;
        ((float2*)fin)[0] = make_float2(M, E);
        ((float2*)fin)[1] = make_float2(I, Mv);
        ((float2*)fin)[2] = make_float2(Ev, Iv);
    }
}

extern "C" void kernel_launch(void* const* d_in, const int* in_sizes, int n_in,
                              void* d_out, int out_size, void* d_ws, size_t ws_size,
                              hipStream_t stream)
{
    const float* init = (const float*)d_in[0];
    const float* dt   = (const float*)d_in[1];
    const int*   ns   = (const int*)d_in[2];
    const int R = in_sizes[0] / 6;  // 200

    dim3 grid((R + 63) / 64), block(128);
    jansen_kernel<<<grid, block, 0, stream>>>(
        init, dt, ns,
        (const float*)d_in[3],  (const float*)d_in[4],
        (const float*)d_in[5],  (const float*)d_in[6],
        (const float*)d_in[7],  (const float*)d_in[8],
        (const float*)d_in[9],  (const float*)d_in[10],
        (const float*)d_in[11], (const float*)d_in[12],
        (const float*)d_in[13], (const float*)d_in[14],
        (float*)d_out, R);
}